// Round 12
// baseline (2258.531 us; speedup 1.0000x reference)
//
#include <hip/hip_runtime.h>
#include <cstdint>
#include <cstddef>

// Problem constants (fixed by the reference)
#define T_STEPS 256
#define BATCH   256
#define DIN     512
#define HID     1024
#define KTOT    1536   // DIN + HID
#define NOUT    4096   // 4*HID
#define BHSZ    ((size_t)BATCH * HID)   // 262144 elems

typedef __bf16 bf16;
typedef __bf16 bf16x4 __attribute__((ext_vector_type(4)));
typedef __bf16 bf16x8 __attribute__((ext_vector_type(8)));
typedef float  f32x4  __attribute__((ext_vector_type(4)));

// cross-XCD-visible bf16 store (write-through to MALL)
__device__ __forceinline__ void store_bf16_sc(bf16* p, bf16 v) {
  unsigned short u = __builtin_bit_cast(unsigned short, v);
  asm volatile("global_store_short %0, %1, off sc0 sc1" :: "v"(p), "v"(u) : "memory");
}

// counted vmcnt wait + scheduler fence (rule #18)
#define VMW_(N) asm volatile("s_waitcnt vmcnt(" #N ")" ::: "memory")
#define VMW(N) do { VMW_(N); __builtin_amdgcn_sched_barrier(0); } while (0)
#define LGKM0() do { asm volatile("s_waitcnt lgkmcnt(0)" ::: "memory"); \
                     __builtin_amdgcn_sched_barrier(0); } while (0)
#define SBAR() __builtin_amdgcn_sched_barrier(0)
// raw workgroup barrier: NO implicit vmcnt(0) drain (unlike __syncthreads)
#define RAWBAR() do { SBAR(); __builtin_amdgcn_s_barrier(); SBAR(); } while (0)

// fast transcendentals (bf16-tolerance OK; saturation-correct)
__device__ __forceinline__ float fexp2(float x) {
  float r; asm("v_exp_f32 %0, %1" : "=v"(r) : "v"(x)); return r;
}
__device__ __forceinline__ float frcp(float x) {
  float r; asm("v_rcp_f32 %0, %1" : "=v"(r) : "v"(x)); return r;
}
__device__ __forceinline__ float fsigmoid(float x) {
  return frcp(1.f + fexp2(-1.44269504f * x));
}
__device__ __forceinline__ float ftanh(float x) {
  return 1.f - 2.f * frcp(1.f + fexp2(2.88539008f * x));
}

// ---------------------------------------------------------------------------
// Gate-interleaved transposed weights: Wt[(j>>4)*64 + gate*16 + (j&15)][k]
__global__ void convert_w_kernel(const float* __restrict__ Wf, const float* __restrict__ Wi,
                                 const float* __restrict__ Wg, const float* __restrict__ Wo,
                                 bf16* __restrict__ Wt) {
  __shared__ float tile[64][17];
  const int k0 = blockIdx.x * 64;
  const int jb = blockIdx.y;
  const int j0 = jb * 16;
  const int t  = threadIdx.x;
  const float* srcs[4] = {Wf, Wi, Wg, Wo};
#pragma unroll
  for (int g = 0; g < 4; ++g) {
    const float* src = srcs[g];
    {
      const int jl = t & 15, kb = t >> 4;
#pragma unroll
      for (int r = 0; r < 4; ++r) {
        const int kl = kb + 16 * r;
        tile[kl][jl] = src[(size_t)(k0 + kl) * HID + (j0 + jl)];
      }
    }
    __syncthreads();
    {
      const int kk = t & 63, jl4 = t >> 6;
#pragma unroll
      for (int r = 0; r < 4; ++r) {
        const int jl = jl4 + 4 * r;
        Wt[(size_t)(jb * 64 + g * 16 + jl) * KTOT + (k0 + kk)] = (bf16)tile[kk][jl];
      }
    }
    __syncthreads();
  }
}

// fp32 -> bf16 convert of X (big-ws path)
__global__ void convert_x_kernel(const float* __restrict__ X, bf16* __restrict__ xb) {
  const int t = blockIdx.y;
  const int i = blockIdx.x * blockDim.x + threadIdx.x;
  const float4 v = ((const float4*)(X + (size_t)t * BATCH * DIN))[i];
  bf16x4 o;
  o[0] = (bf16)v.x; o[1] = (bf16)v.y; o[2] = (bf16)v.z; o[3] = (bf16)v.w;
  ((bf16x4*)(xb + (size_t)t * BATCH * DIN))[i] = o;
}

// ---------------------------------------------------------------------------
// Persistent LSTM v11 = v10 with raw s_barrier instead of __syncthreads in
// the step loop. __syncthreads emits s_waitcnt vmcnt(0) before s_barrier,
// which drained the cross-step x' prefetch inside the barrier every step
// (cold xb slice: L3/HBM latency, serialized across all waves). Raw barrier
// keeps x' in flight; protocol unchanged:
//  - each wave VMW(8)-acks its own stores BEFORE the tail barrier, so tid0's
//    flag after the barrier still implies all block stores MALL-visible
//  - tail barrier still separates reduce-reads from next dump (WAR on redu)
//  - dump barrier gets explicit lgkmcnt(0) for LDS visibility
__global__ __launch_bounds__(512, 2)
void lstm_v11(const bf16* __restrict__ Bt,
              const bf16* __restrict__ xb,
              bf16* __restrict__ hseq,
              const bf16* __restrict__ zb16,     // >= 1MB zeros
              float* __restrict__ outF,
              const float* __restrict__ bf_, const float* __restrict__ bi_,
              const float* __restrict__ bg_, const float* __restrict__ bo_,
              unsigned* __restrict__ flags) {    // [T_STEPS][256], zeroed
  __shared__ f32x4 redu[8][16][64];   // 128 KiB -> 1 block/CU

  const int tid = threadIdx.x, lane = tid & 63, wid = tid >> 6;
  const int bid = blockIdx.x;
  const int e8  = bid & 7;
  const int mblk = e8 >> 1;                      // group on XCD pair {2m,2m+1}
  const int nblk = ((bid >> 3) << 1) | (e8 & 1); // bijective 0..63
  const int bm0 = mblk * 64;
  const int bn0 = nblk * 64;
  const int fr = lane & 15, fq = lane >> 4;

  // once-per-launch agent acquire: invalidate stale L2 lines (graph replays)
  if (tid == 0)
    (void)__hip_atomic_load(flags, __ATOMIC_ACQUIRE, __HIP_MEMORY_SCOPE_AGENT);
  __syncthreads();

  const int j = nblk * 16 + fr;
  const float bfv = bf_[j], biv = bi_[j], bgv = bg_[j], bov = bo_[j];
  float cr[2] = {0.f, 0.f};

  // ---- B panel -> registers, once (96 VGPR/lane)
  bf16x8 breg[6][4];
#pragma unroll
  for (int s = 0; s < 6; ++s) {
    const int ks = wid + 8 * s;
#pragma unroll
    for (int nf = 0; nf < 4; ++nf)
      breg[s][nf] = *(const bf16x8*)(Bt + (size_t)(bn0 + nf * 16 + fr) * KTOT
                                     + ks * 32 + fq * 8);
  }

  // 4 named A slots (static regalloc), 16 VGPR each
  bf16x8 S0[4], S1[4], S2[4], S3[4];

  auto ldx = [&](int t2, int s, bf16x8 (&slot)[4]) {   // s in {0,1}
    const bf16* src = xb + (size_t)t2 * BATCH * DIN + (wid + 8 * s) * 32 + fq * 8;
#pragma unroll
    for (int mf = 0; mf < 4; ++mf)
      slot[mf] = *(const bf16x8*)(src + (size_t)(bm0 + mf * 16 + fr) * DIN);
  };
  auto ldh = [&](int t2, int s, bf16x8 (&slot)[4]) {   // s in {2..5}
    const bf16* base = (t2 == 0) ? zb16 : hseq + (size_t)(t2 - 1) * BHSZ;
    const bf16* src = base + (wid + 8 * s) * 32 - 512 + fq * 8;
#pragma unroll
    for (int mf = 0; mf < 4; ++mf)
      slot[mf] = *(const bf16x8*)(src + (size_t)(bm0 + mf * 16 + fr) * HID);
  };

  // per-wave poll of this wave's 8 h-producers only (lane&7 -> producer id)
  const int pn8 = 2 * wid + ((lane & 7) >> 1) * 16 + (lane & 1);
  auto poll = [&](int tprev) {
    const unsigned* f = flags + (size_t)tprev * 256 + mblk * 64 + pn8;
    const unsigned long long tt0 = __builtin_amdgcn_s_memrealtime();
    for (;;) {
      unsigned v = __hip_atomic_load(f, __ATOMIC_RELAXED,
                                     __HIP_MEMORY_SCOPE_AGENT);
      if (__all(v != 0)) break;
      __builtin_amdgcn_s_sleep(1);
      if (__builtin_amdgcn_s_memrealtime() - tt0 > (1ULL << 22)) break;  // fail-soft
    }
    asm volatile("" ::: "memory");
    __builtin_amdgcn_sched_barrier(0);
  };

#define MFMA16(ACC, SLOT, S) do {                                           \
    __builtin_amdgcn_s_setprio(1);                                          \
    _Pragma("unroll")                                                       \
    for (int mf_ = 0; mf_ < 4; ++mf_) {                                     \
      _Pragma("unroll")                                                     \
      for (int nf_ = 0; nf_ < 4; ++nf_)                                     \
        ACC[mf_][nf_] = __builtin_amdgcn_mfma_f32_16x16x32_bf16(            \
            SLOT[mf_], breg[S][nf_], ACC[mf_][nf_], 0, 0, 0);               \
    }                                                                       \
    __builtin_amdgcn_s_setprio(0);                                          \
  } while (0)

#define STEP(T0, XA, XB, HA, HB, HC, HD, NA, NB) do {                       \
    const int t_ = (T0);                                                    \
    f32x4 acc[4][4] = {};                                                   \
    VMW(4);  MFMA16(acc, XA, 0);                                            \
    VMW(0);  MFMA16(acc, XB, 1);                                            \
    if (t_ > 0) poll(t_ - 1);          /* per-wave, 8 producers */          \
    ldh(t_, 2, HA); ldh(t_, 3, HB); ldh(t_, 4, HC); ldh(t_, 5, HD); SBAR(); \
    VMW(12); MFMA16(acc, HA, 2);                                            \
    VMW(8);  MFMA16(acc, HB, 3);                                            \
    VMW(4);  MFMA16(acc, HC, 4);                                            \
    VMW(0);  MFMA16(acc, HD, 5);                                            \
    /* ---- dump -> RAW barrier -> reduce -> gates -> stores ---- */        \
    _Pragma("unroll")                                                       \
    for (int mf_ = 0; mf_ < 4; ++mf_) {                                     \
      _Pragma("unroll")                                                     \
      for (int nf_ = 0; nf_ < 4; ++nf_)                                     \
        redu[wid][mf_ * 4 + nf_][lane] = acc[mf_][nf_];                     \
    }                                                                       \
    LGKM0();                                                                \
    RAWBAR();                       /* dump visible; no vmcnt drain */      \
    const int fbase_ = (wid >> 1) * 4;                                      \
    const int rh_ = wid & 1;                                                \
    float z_[2][4];                                                         \
    _Pragma("unroll")                                                       \
    for (int e_ = 0; e_ < 2; ++e_) {                                        \
      const int rloc_ = rh_ * 8 + fq * 2 + e_;                              \
      const int lsel_ = (rloc_ >> 2) * 16 + fr;                             \
      const int rc_ = rloc_ & 3;                                            \
      _Pragma("unroll")                                                     \
      for (int nf_ = 0; nf_ < 4; ++nf_) {                                   \
        float sum_ = 0.f;                                                   \
        _Pragma("unroll")                                                   \
        for (int s_ = 0; s_ < 8; ++s_)                                      \
          sum_ += ((const float*)&redu[s_][fbase_ + nf_][lsel_])[rc_];      \
        z_[e_][nf_] = sum_;                                                 \
      }                                                                     \
    }                                                                       \
    float* outSl_ = outF + (size_t)t_ * BHSZ;                               \
    _Pragma("unroll")                                                       \
    for (int e_ = 0; e_ < 2; ++e_) {                                        \
      const float fg_ = fsigmoid(z_[e_][0] + bfv);                          \
      const float ig_ = fsigmoid(z_[e_][1] + biv);                          \
      const float gg_ = ftanh(z_[e_][2] + bgv);                             \
      const float og_ = fsigmoid(z_[e_][3] + bov);                          \
      cr[e_] = fg_ * cr[e_] + ig_ * gg_;                                    \
      const float h_ = og_ * ftanh(cr[e_]);                                 \
      const int m_ = bm0 + wid * 8 + fq * 2 + e_;                           \
      const size_t off_ = (size_t)m_ * HID + j;                             \
      outSl_[off_] = h_;                                                    \
      store_bf16_sc(hseq + (size_t)t_ * BHSZ + off_, (bf16)h_);             \
      if (t_ == T_STEPS - 1)                                                \
        outF[(size_t)(T_STEPS + 1) * BHSZ + off_] = cr[e_];                 \
    }                                                                       \
    if (t_ + 1 < T_STEPS) {                                                 \
      ldx(t_ + 1, 0, NA); ldx(t_ + 1, 1, NB); SBAR();                       \
      VMW(8);      /* 12 outstanding -> 8: the 4 stores are acked */        \
    } else {                                                                \
      VMW(0);                                                               \
    }                                                                       \
    RAWBAR();        /* all waves store-acked; x' loads STAY in flight */   \
    if (tid == 0)                                                           \
      __hip_atomic_store(&flags[(size_t)t_ * 256 + mblk * 64 + nblk], 1u,   \
                         __ATOMIC_RELAXED, __HIP_MEMORY_SCOPE_AGENT);       \
  } while (0)

  // prologue: x slices of step 0
  ldx(0, 0, S0); SBAR();
  ldx(0, 1, S1); SBAR();

#pragma unroll 1
  for (int t = 0; t < T_STEPS; t += 2) {
    STEP(t,     S0, S1, S2, S3, S0, S1, S2, S3);
    STEP(t + 1, S2, S3, S0, S1, S2, S3, S0, S1);
  }
#undef STEP
#undef MFMA16
}

// ---------------------------------------------------------------------------
// Fallback (small ws): round-5 MODE-1 path verbatim (fp32 A from X / out).
__global__ __launch_bounds__(512, 2)
void lstm_fb(const bf16* __restrict__ Bt,
             const float* __restrict__ X,
             const float* __restrict__ zbF,
             float* __restrict__ outF,
             const float* __restrict__ bf_, const float* __restrict__ bi_,
             const float* __restrict__ bg_, const float* __restrict__ bo_,
             unsigned* __restrict__ flags) {
  __shared__ f32x4 redu[8][16][64];
  const int tid = threadIdx.x, lane = tid & 63, wid = tid >> 6;
  const int bid = blockIdx.x;
  const int xcd = bid & 7, sl = bid >> 3;
  const int nblk = xcd * 8 + (sl & 7);
  const int mblk = sl >> 3;
  const int bm0 = mblk * 64;
  const int bn0 = nblk * 64;
  const int fr = lane & 15, fq = lane >> 4;

  if (tid == 0)
    (void)__hip_atomic_load(flags, __ATOMIC_ACQUIRE, __HIP_MEMORY_SCOPE_AGENT);
  __syncthreads();

  const int j = nblk * 16 + fr;
  const float bfv = bf_[j], biv = bi_[j], bgv = bg_[j], bov = bo_[j];
  float cr[2] = {0.f, 0.f};

  bf16x8 breg[6][4];
#pragma unroll
  for (int s = 0; s < 6; ++s) {
    const int ks = wid + 8 * s;
#pragma unroll
    for (int nf = 0; nf < 4; ++nf)
      breg[s][nf] = *(const bf16x8*)(Bt + (size_t)(bn0 + nf * 16 + fr) * KTOT
                                     + ks * 32 + fq * 8);
  }

  bf16x8 afp[2][4];

  auto poll = [&](int tprev) {
    const unsigned* f = flags + (size_t)tprev * 256 + mblk * 64;
    const unsigned long long tt0 = __builtin_amdgcn_s_memrealtime();
    for (;;) {
      unsigned v = __hip_atomic_load(f + lane, __ATOMIC_RELAXED,
                                     __HIP_MEMORY_SCOPE_AGENT);
      if (__all(v != 0)) break;
      __builtin_amdgcn_s_sleep(2);
      if (__builtin_amdgcn_s_memrealtime() - tt0 > (1ULL << 22)) break;
    }
    asm volatile("" ::: "memory");
    __builtin_amdgcn_sched_barrier(0);
  };

  auto loadA = [&](int t2, int s, int p) __attribute__((always_inline)) {
    const int ks = wid + 8 * s;
    const int k = ks * 32 + fq * 8;
    if (s == 2 && t2 > 0) poll(t2 - 1);
    const float* src; int ld, kk;
    if (s < 2) { src = X + (size_t)t2 * BATCH * DIN; ld = DIN; kk = k; }
    else {
      src = (t2 == 0) ? zbF : outF + (size_t)(t2 - 1) * BHSZ;
      ld = HID; kk = k - 512;
    }
#pragma unroll
    for (int mf = 0; mf < 4; ++mf) {
      const float* q = src + (size_t)(bm0 + mf * 16 + fr) * ld + kk;
      const f32x4 lo = *(const f32x4*)q;
      const f32x4 hi = *(const f32x4*)(q + 4);
      bf16x8 v;
      v[0] = (bf16)lo[0]; v[1] = (bf16)lo[1]; v[2] = (bf16)lo[2]; v[3] = (bf16)lo[3];
      v[4] = (bf16)hi[0]; v[5] = (bf16)hi[1]; v[6] = (bf16)hi[2]; v[7] = (bf16)hi[3];
      afp[p][mf] = v;
    }
  };

  loadA(0, 0, 0);

#pragma unroll 1
  for (int t = 0; t < T_STEPS; ++t) {
    f32x4 acc[4][4] = {};
#pragma unroll
    for (int s = 0; s < 6; ++s) {
      if (s < 5)                loadA(t, s + 1, (s + 1) & 1);
      else if (t + 1 < T_STEPS) loadA(t + 1, 0, 0);
      __builtin_amdgcn_s_setprio(1);
#pragma unroll
      for (int mf = 0; mf < 4; ++mf)
#pragma unroll
        for (int nf = 0; nf < 4; ++nf)
          acc[mf][nf] = __builtin_amdgcn_mfma_f32_16x16x32_bf16(
              afp[s & 1][mf], breg[s][nf], acc[mf][nf], 0, 0, 0);
      __builtin_amdgcn_s_setprio(0);
    }

#pragma unroll
    for (int mf = 0; mf < 4; ++mf)
#pragma unroll
      for (int nf = 0; nf < 4; ++nf)
        redu[wid][mf * 4 + nf][lane] = acc[mf][nf];
    __syncthreads();

    const int fbase = (wid >> 1) * 4;
    const int rh = wid & 1;
    float z[2][4];
#pragma unroll
    for (int e = 0; e < 2; ++e) {
      const int rloc = rh * 8 + fq * 2 + e;
      const int lsel = (rloc >> 2) * 16 + fr;
      const int rc = rloc & 3;
#pragma unroll
      for (int nf = 0; nf < 4; ++nf) {
        float sum = 0.f;
#pragma unroll
        for (int s = 0; s < 8; ++s)
          sum += ((const float*)&redu[s][fbase + nf][lsel])[rc];
        z[e][nf] = sum;
      }
    }

    float* outSl = outF + (size_t)t * BHSZ;
#pragma unroll
    for (int e = 0; e < 2; ++e) {
      const float fg = 1.f / (1.f + expf(-(z[e][0] + bfv)));
      const float ig = 1.f / (1.f + expf(-(z[e][1] + biv)));
      const float gg = tanhf(z[e][2] + bgv);
      const float og = 1.f / (1.f + expf(-(z[e][3] + bov)));
      cr[e] = fg * cr[e] + ig * gg;
      const float h = og * tanhf(cr[e]);
      const int m = bm0 + wid * 8 + fq * 2 + e;
      const size_t off = (size_t)m * HID + j;
      __hip_atomic_store(&outSl[off], h, __ATOMIC_RELAXED,
                         __HIP_MEMORY_SCOPE_AGENT);
      if (t == T_STEPS - 1)
        outF[(size_t)(T_STEPS + 1) * BHSZ + off] = cr[e];
    }
    asm volatile("s_waitcnt vmcnt(0)" ::: "memory");
    __syncthreads();
    if (tid == 0)
      __hip_atomic_store(&flags[(size_t)t * 256 + mblk * 64 + nblk], 1u,
                         __ATOMIC_RELAXED, __HIP_MEMORY_SCOPE_AGENT);
  }
}

// ---------------------------------------------------------------------------
extern "C" void kernel_launch(void* const* d_in, const int* in_sizes, int n_in,
                              void* d_out, int out_size, void* d_ws, size_t ws_size,
                              hipStream_t stream) {
  const float* X   = (const float*)d_in[0];
  const float* Wf  = (const float*)d_in[1];
  const float* bf_ = (const float*)d_in[2];
  const float* Wi  = (const float*)d_in[3];
  const float* bi_ = (const float*)d_in[4];
  const float* Wg  = (const float*)d_in[5];
  const float* bg_ = (const float*)d_in[6];
  const float* Wo  = (const float*)d_in[7];
  const float* bo_ = (const float*)d_in[8];
  float* out = (float*)d_out;

  const size_t WtB   = (size_t)NOUT * KTOT * 2;            // 12.58 MB
  const size_t zBb   = BHSZ * 4;                           // 1 MB zeros
  const size_t flagB = (size_t)T_STEPS * 256 * 4;          // 256 KB
  const size_t XbB   = (size_t)T_STEPS * BATCH * DIN * 2;  // 67.1 MB
  const size_t HsB   = (size_t)T_STEPS * BHSZ * 2;         // 134.2 MB

  char* ws = (char*)d_ws;
  bf16*     Wt    = (bf16*)ws;              ws += WtB;
  float*    zbF   = (float*)(void*)ws;      ws += zBb;
  unsigned* flags = (unsigned*)(void*)ws;   ws += flagB;

  const bool big = ws_size >= WtB + zBb + flagB + XbB + HsB + (1u << 20);
  bf16* xbp = nullptr;  bf16* hseq = nullptr;
  if (big) {
    xbp  = (bf16*)ws;   ws += XbB;
    hseq = (bf16*)ws;
  }

  // zeros + flags (re-zeroed every launch -> deterministic)
  hipMemsetAsync(zbF, 0, zBb + flagB, stream);

  convert_w_kernel<<<dim3(KTOT / 64, NOUT / 64), 256, 0, stream>>>(Wf, Wi, Wg, Wo, Wt);

  if (big) {
    convert_x_kernel<<<dim3(BATCH * DIN / 4 / 256, T_STEPS), 256, 0, stream>>>(X, xbp);
    lstm_v11<<<256, 512, 0, stream>>>(Wt, xbp, hseq, (const bf16*)zbF, out,
                                      bf_, bi_, bg_, bo_, flags);
  } else {
    lstm_fb<<<256, 512, 0, stream>>>(Wt, X, zbF, out,
                                     bf_, bi_, bg_, bo_, flags);
  }

  // hx = outputs[T-1] (cx stored by the kernel)
  hipMemcpyAsync(out + (size_t)T_STEPS * BHSZ, out + (size_t)(T_STEPS - 1) * BHSZ,
                 BHSZ * 4, hipMemcpyDeviceToDevice, stream);
}

// Round 13
// 2062.290 us; speedup vs baseline: 1.0952x; 1.0952x over previous
//
#include <hip/hip_runtime.h>
#include <cstdint>
#include <cstddef>

// Problem constants (fixed by the reference)
#define T_STEPS 256
#define BATCH   256
#define DIN     512
#define HID     1024
#define KTOT    1536   // DIN + HID
#define NOUT    4096   // 4*HID
#define BHSZ    ((size_t)BATCH * HID)   // 262144 elems

typedef __bf16 bf16;
typedef __bf16 bf16x4 __attribute__((ext_vector_type(4)));
typedef __bf16 bf16x8 __attribute__((ext_vector_type(8)));
typedef float  f32x4  __attribute__((ext_vector_type(4)));

// cross-XCD-visible bf16 store (write-through to MALL)
__device__ __forceinline__ void store_bf16_sc(bf16* p, bf16 v) {
  unsigned short u = __builtin_bit_cast(unsigned short, v);
  asm volatile("global_store_short %0, %1, off sc0 sc1" :: "v"(p), "v"(u) : "memory");
}

// counted vmcnt wait + scheduler fence (rule #18)
#define VMW_(N) asm volatile("s_waitcnt vmcnt(" #N ")" ::: "memory")
#define VMW(N) do { VMW_(N); __builtin_amdgcn_sched_barrier(0); } while (0)
#define LGKM0() do { asm volatile("s_waitcnt lgkmcnt(0)" ::: "memory"); \
                     __builtin_amdgcn_sched_barrier(0); } while (0)
#define SBAR() __builtin_amdgcn_sched_barrier(0)
// raw workgroup barrier: NO implicit vmcnt(0) drain (unlike __syncthreads)
#define RAWBAR() do { SBAR(); __builtin_amdgcn_s_barrier(); SBAR(); } while (0)

// fast transcendentals (bf16-tolerance OK; saturation-correct)
__device__ __forceinline__ float fexp2(float x) {
  float r; asm("v_exp_f32 %0, %1" : "=v"(r) : "v"(x)); return r;
}
__device__ __forceinline__ float frcp(float x) {
  float r; asm("v_rcp_f32 %0, %1" : "=v"(r) : "v"(x)); return r;
}
__device__ __forceinline__ float fsigmoid(float x) {
  return frcp(1.f + fexp2(-1.44269504f * x));
}
__device__ __forceinline__ float ftanh(float x) {
  return 1.f - 2.f * frcp(1.f + fexp2(2.88539008f * x));
}

// ---------------------------------------------------------------------------
// Gate-interleaved transposed weights: Wt[(j>>4)*64 + gate*16 + (j&15)][k]
__global__ void convert_w_kernel(const float* __restrict__ Wf, const float* __restrict__ Wi,
                                 const float* __restrict__ Wg, const float* __restrict__ Wo,
                                 bf16* __restrict__ Wt) {
  __shared__ float tile[64][17];
  const int k0 = blockIdx.x * 64;
  const int jb = blockIdx.y;
  const int j0 = jb * 16;
  const int t  = threadIdx.x;
  const float* srcs[4] = {Wf, Wi, Wg, Wo};
#pragma unroll
  for (int g = 0; g < 4; ++g) {
    const float* src = srcs[g];
    {
      const int jl = t & 15, kb = t >> 4;
#pragma unroll
      for (int r = 0; r < 4; ++r) {
        const int kl = kb + 16 * r;
        tile[kl][jl] = src[(size_t)(k0 + kl) * HID + (j0 + jl)];
      }
    }
    __syncthreads();
    {
      const int kk = t & 63, jl4 = t >> 6;
#pragma unroll
      for (int r = 0; r < 4; ++r) {
        const int jl = jl4 + 4 * r;
        Wt[(size_t)(jb * 64 + g * 16 + jl) * KTOT + (k0 + kk)] = (bf16)tile[kk][jl];
      }
    }
    __syncthreads();
  }
}

// fp32 -> bf16 convert of X (big-ws path)
__global__ void convert_x_kernel(const float* __restrict__ X, bf16* __restrict__ xb) {
  const int t = blockIdx.y;
  const int i = blockIdx.x * blockDim.x + threadIdx.x;
  const float4 v = ((const float4*)(X + (size_t)t * BATCH * DIN))[i];
  bf16x4 o;
  o[0] = (bf16)v.x; o[1] = (bf16)v.y; o[2] = (bf16)v.z; o[3] = (bf16)v.w;
  ((bf16x4*)(xb + (size_t)t * BATCH * DIN))[i] = o;
}

// ---------------------------------------------------------------------------
// Persistent LSTM v12 = v10/v11 skeleton + tiled handoff data path.
//  - hseq tiled: hs[t][mblk*64+nblk][64rows][16j] (2KB/block-step, contiguous)
//  - owner remap (lane -> row w*8+4e+fq, col fr): each hseq store instr is
//    ONE full 128B line (tile[w*128+e*64+lane]); h-stores issued BEFORE out
//    stores; VMW(10) acks only the h-lines before the flag
//  - ldh reads from producer tiles: 16 MALL lines/instr instead of 64
//  - reduce-read lane pattern now 2-way on banks (free) instead of 4-way
// Protocol unchanged from v10: per-block u32 flag, per-wave 8-producer poll.
__global__ __launch_bounds__(512, 2)
void lstm_v12(const bf16* __restrict__ Bt,
              const bf16* __restrict__ xb,
              bf16* __restrict__ hseq,           // tiled, big path only
              const bf16* __restrict__ zb16,     // >= 2KB zeros
              float* __restrict__ outF,
              const float* __restrict__ bf_, const float* __restrict__ bi_,
              const float* __restrict__ bg_, const float* __restrict__ bo_,
              unsigned* __restrict__ flags) {    // [T_STEPS][256], zeroed
  __shared__ f32x4 redu[8][16][64];   // 128 KiB -> 1 block/CU

  const int tid = threadIdx.x, lane = tid & 63, wid = tid >> 6;
  const int bid = blockIdx.x;
  const int e8  = bid & 7;
  const int mblk = e8 >> 1;                      // group on XCD pair {2m,2m+1}
  const int nblk = ((bid >> 3) << 1) | (e8 & 1); // bijective 0..63
  const int bm0 = mblk * 64;
  const int bn0 = nblk * 64;
  const int fr = lane & 15, fq = lane >> 4;

  // once-per-launch agent acquire: invalidate stale L2 lines (graph replays)
  if (tid == 0)
    (void)__hip_atomic_load(flags, __ATOMIC_ACQUIRE, __HIP_MEMORY_SCOPE_AGENT);
  __syncthreads();

  const int j = nblk * 16 + fr;
  const float bfv = bf_[j], biv = bi_[j], bgv = bg_[j], bov = bo_[j];
  float cr[2] = {0.f, 0.f};   // cells (row bm0+wid*8+4e+fq, col j)

  // ---- B panel -> registers, once (96 VGPR/lane)
  bf16x8 breg[6][4];
#pragma unroll
  for (int s = 0; s < 6; ++s) {
    const int ks = wid + 8 * s;
#pragma unroll
    for (int nf = 0; nf < 4; ++nf)
      breg[s][nf] = *(const bf16x8*)(Bt + (size_t)(bn0 + nf * 16 + fr) * KTOT
                                     + ks * 32 + fq * 8);
  }

  // 4 named A slots (static regalloc), 16 VGPR each
  bf16x8 S0[4], S1[4], S2[4], S3[4];

  auto ldx = [&](int t2, int s, bf16x8 (&slot)[4]) {   // s in {0,1}
    const bf16* src = xb + (size_t)t2 * BATCH * DIN + (wid + 8 * s) * 32 + fq * 8;
#pragma unroll
    for (int mf = 0; mf < 4; ++mf)
      slot[mf] = *(const bf16x8*)(src + (size_t)(bm0 + mf * 16 + fr) * DIN);
  };
  // h loads from producer TILES. Slice s in {2..5}: global h-cols
  // [(wid+8s)*32-512, +32) = producers p, p+1 (16 cols each, same mblk).
  auto ldh = [&](int t2, int s, bf16x8 (&slot)[4]) {
    const int c0 = (wid + 8 * s) * 32 - 512;       // multiple of 32
    const int pp = (c0 >> 4) + (fq >> 1);          // fq 0,1 -> p; 2,3 -> p+1
    const bf16* base = (t2 == 0)
        ? zb16
        : hseq + (((size_t)(t2 - 1) << 8) + mblk * 64 + pp) * 1024;
    const int coloff = (fq & 1) * 8;
#pragma unroll
    for (int mf = 0; mf < 4; ++mf)
      slot[mf] = *(const bf16x8*)(base + (mf * 16 + fr) * 16 + coloff);
  };

  // per-wave poll of this wave's 8 h-producers only (lane&7 -> producer id)
  const int pn8 = 2 * wid + ((lane & 7) >> 1) * 16 + (lane & 1);
  auto poll = [&](int tprev) {
    const unsigned* f = flags + (size_t)tprev * 256 + mblk * 64 + pn8;
    const unsigned long long tt0 = __builtin_amdgcn_s_memrealtime();
    for (;;) {
      unsigned v = __hip_atomic_load(f, __ATOMIC_RELAXED,
                                     __HIP_MEMORY_SCOPE_AGENT);
      if (__all(v != 0)) break;
      __builtin_amdgcn_s_sleep(1);
      if (__builtin_amdgcn_s_memrealtime() - tt0 > (1ULL << 22)) break;  // fail-soft
    }
    asm volatile("" ::: "memory");
    __builtin_amdgcn_sched_barrier(0);
  };

#define MFMA16(ACC, SLOT, S) do {                                           \
    __builtin_amdgcn_s_setprio(1);                                          \
    _Pragma("unroll")                                                       \
    for (int mf_ = 0; mf_ < 4; ++mf_) {                                     \
      _Pragma("unroll")                                                     \
      for (int nf_ = 0; nf_ < 4; ++nf_)                                     \
        ACC[mf_][nf_] = __builtin_amdgcn_mfma_f32_16x16x32_bf16(            \
            SLOT[mf_], breg[S][nf_], ACC[mf_][nf_], 0, 0, 0);               \
    }                                                                       \
    __builtin_amdgcn_s_setprio(0);                                          \
  } while (0)

// Steady-state per-wave VMEM queue:
//  entry: [o0,o1, x(8)] (+flag for wave0) -> VMW(4): x s0 ready; VMW(0): s1
//  poll (queue empty) -> ldh 16 -> VMW(12/8/4/0) ladder
//  tail: h-stores(2, full-line) -> out stores(2) -> ldx(8) -> VMW(10):
//        h-lines acked (oldest), out + x' stay in flight -> RAWBAR -> flag
#define STEP(T0, XA, XB, HA, HB, HC, HD, NA, NB) do {                       \
    const int t_ = (T0);                                                    \
    f32x4 acc[4][4] = {};                                                   \
    VMW(4);  MFMA16(acc, XA, 0);                                            \
    VMW(0);  MFMA16(acc, XB, 1);                                            \
    if (t_ > 0) poll(t_ - 1);          /* per-wave, 8 producers */          \
    ldh(t_, 2, HA); ldh(t_, 3, HB); ldh(t_, 4, HC); ldh(t_, 5, HD); SBAR(); \
    VMW(12); MFMA16(acc, HA, 2);                                            \
    VMW(8);  MFMA16(acc, HB, 3);                                            \
    VMW(4);  MFMA16(acc, HC, 4);                                            \
    VMW(0);  MFMA16(acc, HD, 5);                                            \
    /* ---- dump -> RAW barrier -> reduce -> gates ---- */                  \
    _Pragma("unroll")                                                       \
    for (int mf_ = 0; mf_ < 4; ++mf_) {                                     \
      _Pragma("unroll")                                                     \
      for (int nf_ = 0; nf_ < 4; ++nf_)                                     \
        redu[wid][mf_ * 4 + nf_][lane] = acc[mf_][nf_];                     \
    }                                                                       \
    LGKM0();                                                                \
    RAWBAR();                                                               \
    const int mfo_ = wid >> 1;                                              \
    float hv_[2];                                                           \
    _Pragma("unroll")                                                       \
    for (int e_ = 0; e_ < 2; ++e_) {                                        \
      /* cell: row-in-frag rho = (wid&1)*8 + 4e + fq, col fr; rc == fq */   \
      const int lsel_ = (((wid & 1) << 1) + e_) * 16 + fr;                  \
      float z_[4];                                                          \
      _Pragma("unroll")                                                     \
      for (int nf_ = 0; nf_ < 4; ++nf_) {                                   \
        float sum_ = 0.f;                                                   \
        _Pragma("unroll")                                                   \
        for (int s_ = 0; s_ < 8; ++s_)                                      \
          sum_ += ((const float*)&redu[s_][mfo_ * 4 + nf_][lsel_])[fq];     \
        z_[nf_] = sum_;                                                     \
      }                                                                     \
      const float fg_ = fsigmoid(z_[0] + bfv);                              \
      const float ig_ = fsigmoid(z_[1] + biv);                              \
      const float gg_ = ftanh(z_[2] + bgv);                                 \
      const float og_ = fsigmoid(z_[3] + bov);                              \
      cr[e_] = fg_ * cr[e_] + ig_ * gg_;                                    \
      hv_[e_] = og_ * ftanh(cr[e_]);                                        \
    }                                                                       \
    /* h-stores first (each = ONE full 128B line), then out stores */       \
    bf16* tile_ = hseq + (((size_t)t_ << 8) + mblk * 64 + nblk) * 1024;     \
    store_bf16_sc(&tile_[wid * 128 + lane], (bf16)hv_[0]);                  \
    store_bf16_sc(&tile_[wid * 128 + 64 + lane], (bf16)hv_[1]);             \
    float* outSl_ = outF + (size_t)t_ * BHSZ;                               \
    _Pragma("unroll")                                                       \
    for (int e_ = 0; e_ < 2; ++e_) {                                        \
      const size_t off_ = (size_t)(bm0 + wid * 8 + e_ * 4 + fq) * HID + j;  \
      outSl_[off_] = hv_[e_];                                               \
      if (t_ == T_STEPS - 1)                                                \
        outF[(size_t)(T_STEPS + 1) * BHSZ + off_] = cr[e_];                 \
    }                                                                       \
    if (t_ + 1 < T_STEPS) {                                                 \
      ldx(t_ + 1, 0, NA); ldx(t_ + 1, 1, NB); SBAR();                       \
      VMW(10);     /* 12 outstanding -> 10: the 2 h-line stores acked */    \
    } else {                                                                \
      VMW(0);                                                               \
    }                                                                       \
    RAWBAR();                                                               \
    if (tid == 0)                                                           \
      __hip_atomic_store(&flags[(size_t)t_ * 256 + mblk * 64 + nblk], 1u,   \
                         __ATOMIC_RELAXED, __HIP_MEMORY_SCOPE_AGENT);       \
  } while (0)

  // prologue: x slices of step 0
  ldx(0, 0, S0); SBAR();
  ldx(0, 1, S1); SBAR();

#pragma unroll 1
  for (int t = 0; t < T_STEPS; t += 2) {
    STEP(t,     S0, S1, S2, S3, S0, S1, S2, S3);
    STEP(t + 1, S2, S3, S0, S1, S2, S3, S0, S1);
  }
#undef STEP
#undef MFMA16
}

// ---------------------------------------------------------------------------
// Fallback (small ws): round-5 MODE-1 path verbatim (fp32 A from X / out).
__global__ __launch_bounds__(512, 2)
void lstm_fb(const bf16* __restrict__ Bt,
             const float* __restrict__ X,
             const float* __restrict__ zbF,
             float* __restrict__ outF,
             const float* __restrict__ bf_, const float* __restrict__ bi_,
             const float* __restrict__ bg_, const float* __restrict__ bo_,
             unsigned* __restrict__ flags) {
  __shared__ f32x4 redu[8][16][64];
  const int tid = threadIdx.x, lane = tid & 63, wid = tid >> 6;
  const int bid = blockIdx.x;
  const int xcd = bid & 7, sl = bid >> 3;
  const int nblk = xcd * 8 + (sl & 7);
  const int mblk = sl >> 3;
  const int bm0 = mblk * 64;
  const int bn0 = nblk * 64;
  const int fr = lane & 15, fq = lane >> 4;

  if (tid == 0)
    (void)__hip_atomic_load(flags, __ATOMIC_ACQUIRE, __HIP_MEMORY_SCOPE_AGENT);
  __syncthreads();

  const int j = nblk * 16 + fr;
  const float bfv = bf_[j], biv = bi_[j], bgv = bg_[j], bov = bo_[j];
  float cr[2] = {0.f, 0.f};

  bf16x8 breg[6][4];
#pragma unroll
  for (int s = 0; s < 6; ++s) {
    const int ks = wid + 8 * s;
#pragma unroll
    for (int nf = 0; nf < 4; ++nf)
      breg[s][nf] = *(const bf16x8*)(Bt + (size_t)(bn0 + nf * 16 + fr) * KTOT
                                     + ks * 32 + fq * 8);
  }

  bf16x8 afp[2][4];

  auto poll = [&](int tprev) {
    const unsigned* f = flags + (size_t)tprev * 256 + mblk * 64;
    const unsigned long long tt0 = __builtin_amdgcn_s_memrealtime();
    for (;;) {
      unsigned v = __hip_atomic_load(f + lane, __ATOMIC_RELAXED,
                                     __HIP_MEMORY_SCOPE_AGENT);
      if (__all(v != 0)) break;
      __builtin_amdgcn_s_sleep(2);
      if (__builtin_amdgcn_s_memrealtime() - tt0 > (1ULL << 22)) break;
    }
    asm volatile("" ::: "memory");
    __builtin_amdgcn_sched_barrier(0);
  };

  auto loadA = [&](int t2, int s, int p) __attribute__((always_inline)) {
    const int ks = wid + 8 * s;
    const int k = ks * 32 + fq * 8;
    if (s == 2 && t2 > 0) poll(t2 - 1);
    const float* src; int ld, kk;
    if (s < 2) { src = X + (size_t)t2 * BATCH * DIN; ld = DIN; kk = k; }
    else {
      src = (t2 == 0) ? zbF : outF + (size_t)(t2 - 1) * BHSZ;
      ld = HID; kk = k - 512;
    }
#pragma unroll
    for (int mf = 0; mf < 4; ++mf) {
      const float* q = src + (size_t)(bm0 + mf * 16 + fr) * ld + kk;
      const f32x4 lo = *(const f32x4*)q;
      const f32x4 hi = *(const f32x4*)(q + 4);
      bf16x8 v;
      v[0] = (bf16)lo[0]; v[1] = (bf16)lo[1]; v[2] = (bf16)lo[2]; v[3] = (bf16)lo[3];
      v[4] = (bf16)hi[0]; v[5] = (bf16)hi[1]; v[6] = (bf16)hi[2]; v[7] = (bf16)hi[3];
      afp[p][mf] = v;
    }
  };

  loadA(0, 0, 0);

#pragma unroll 1
  for (int t = 0; t < T_STEPS; ++t) {
    f32x4 acc[4][4] = {};
#pragma unroll
    for (int s = 0; s < 6; ++s) {
      if (s < 5)                loadA(t, s + 1, (s + 1) & 1);
      else if (t + 1 < T_STEPS) loadA(t + 1, 0, 0);
      __builtin_amdgcn_s_setprio(1);
#pragma unroll
      for (int mf = 0; mf < 4; ++mf)
#pragma unroll
        for (int nf = 0; nf < 4; ++nf)
          acc[mf][nf] = __builtin_amdgcn_mfma_f32_16x16x32_bf16(
              afp[s & 1][mf], breg[s][nf], acc[mf][nf], 0, 0, 0);
      __builtin_amdgcn_s_setprio(0);
    }

#pragma unroll
    for (int mf = 0; mf < 4; ++mf)
#pragma unroll
      for (int nf = 0; nf < 4; ++nf)
        redu[wid][mf * 4 + nf][lane] = acc[mf][nf];
    __syncthreads();

    const int fbase = (wid >> 1) * 4;
    const int rh = wid & 1;
    float z[2][4];
#pragma unroll
    for (int e = 0; e < 2; ++e) {
      const int rloc = rh * 8 + fq * 2 + e;
      const int lsel = (rloc >> 2) * 16 + fr;
      const int rc = rloc & 3;
#pragma unroll
      for (int nf = 0; nf < 4; ++nf) {
        float sum = 0.f;
#pragma unroll
        for (int s = 0; s < 8; ++s)
          sum += ((const float*)&redu[s][fbase + nf][lsel])[rc];
        z[e][nf] = sum;
      }
    }

    float* outSl = outF + (size_t)t * BHSZ;
#pragma unroll
    for (int e = 0; e < 2; ++e) {
      const float fg = 1.f / (1.f + expf(-(z[e][0] + bfv)));
      const float ig = 1.f / (1.f + expf(-(z[e][1] + biv)));
      const float gg = tanhf(z[e][2] + bgv);
      const float og = 1.f / (1.f + expf(-(z[e][3] + bov)));
      cr[e] = fg * cr[e] + ig * gg;
      const float h = og * tanhf(cr[e]);
      const int m = bm0 + wid * 8 + fq * 2 + e;
      const size_t off = (size_t)m * HID + j;
      __hip_atomic_store(&outSl[off], h, __ATOMIC_RELAXED,
                         __HIP_MEMORY_SCOPE_AGENT);
      if (t == T_STEPS - 1)
        outF[(size_t)(T_STEPS + 1) * BHSZ + off] = cr[e];
    }
    asm volatile("s_waitcnt vmcnt(0)" ::: "memory");
    __syncthreads();
    if (tid == 0)
      __hip_atomic_store(&flags[(size_t)t * 256 + mblk * 64 + nblk], 1u,
                         __ATOMIC_RELAXED, __HIP_MEMORY_SCOPE_AGENT);
  }
}

// ---------------------------------------------------------------------------
extern "C" void kernel_launch(void* const* d_in, const int* in_sizes, int n_in,
                              void* d_out, int out_size, void* d_ws, size_t ws_size,
                              hipStream_t stream) {
  const float* X   = (const float*)d_in[0];
  const float* Wf  = (const float*)d_in[1];
  const float* bf_ = (const float*)d_in[2];
  const float* Wi  = (const float*)d_in[3];
  const float* bi_ = (const float*)d_in[4];
  const float* Wg  = (const float*)d_in[5];
  const float* bg_ = (const float*)d_in[6];
  const float* Wo  = (const float*)d_in[7];
  const float* bo_ = (const float*)d_in[8];
  float* out = (float*)d_out;

  const size_t WtB   = (size_t)NOUT * KTOT * 2;            // 12.58 MB
  const size_t zBb   = BHSZ * 4;                           // 1 MB zeros
  const size_t flagB = (size_t)T_STEPS * 256 * 4;          // 256 KB
  const size_t XbB   = (size_t)T_STEPS * BATCH * DIN * 2;  // 67.1 MB
  const size_t HsB   = (size_t)T_STEPS * 256 * 1024 * 2;   // 134.2 MB (tiled)

  char* ws = (char*)d_ws;
  bf16*     Wt    = (bf16*)ws;              ws += WtB;
  float*    zbF   = (float*)(void*)ws;      ws += zBb;
  unsigned* flags = (unsigned*)(void*)ws;   ws += flagB;

  const bool big = ws_size >= WtB + zBb + flagB + XbB + HsB + (1u << 20);
  bf16* xbp = nullptr;  bf16* hseq = nullptr;
  if (big) {
    xbp  = (bf16*)ws;   ws += XbB;
    hseq = (bf16*)ws;
  }

  // zeros + flags (re-zeroed every launch -> deterministic)
  hipMemsetAsync(zbF, 0, zBb + flagB, stream);

  convert_w_kernel<<<dim3(KTOT / 64, NOUT / 64), 256, 0, stream>>>(Wf, Wi, Wg, Wo, Wt);

  if (big) {
    convert_x_kernel<<<dim3(BATCH * DIN / 4 / 256, T_STEPS), 256, 0, stream>>>(X, xbp);
    lstm_v12<<<256, 512, 0, stream>>>(Wt, xbp, hseq, (const bf16*)zbF, out,
                                      bf_, bi_, bg_, bo_, flags);
  } else {
    lstm_fb<<<256, 512, 0, stream>>>(Wt, X, zbF, out,
                                     bf_, bi_, bg_, bo_, flags);
  }

  // hx = outputs[T-1] (cx stored by the kernel)
  hipMemcpyAsync(out + (size_t)T_STEPS * BHSZ, out + (size_t)(T_STEPS - 1) * BHSZ,
                 BHSZ * 4, hipMemcpyDeviceToDevice, stream);
}

// Round 14
// 1902.084 us; speedup vs baseline: 1.1874x; 1.0842x over previous
//
#include <hip/hip_runtime.h>
#include <cstdint>
#include <cstddef>

// Problem constants (fixed by the reference)
#define T_STEPS 256
#define BATCH   256
#define DIN     512
#define HID     1024
#define KTOT    1536   // DIN + HID
#define NOUT    4096   // 4*HID
#define BHSZ    ((size_t)BATCH * HID)   // 262144 elems

typedef __bf16 bf16;
typedef __bf16 bf16x4 __attribute__((ext_vector_type(4)));
typedef __bf16 bf16x8 __attribute__((ext_vector_type(8)));
typedef float  f32x4  __attribute__((ext_vector_type(4)));

// cross-XCD-visible bf16 store (write-through to MALL)
__device__ __forceinline__ void store_bf16_sc(bf16* p, bf16 v) {
  unsigned short u = __builtin_bit_cast(unsigned short, v);
  asm volatile("global_store_short %0, %1, off sc0 sc1" :: "v"(p), "v"(u) : "memory");
}

// counted vmcnt wait + scheduler fence (rule #18)
#define VMW_(N) asm volatile("s_waitcnt vmcnt(" #N ")" ::: "memory")
#define VMW(N) do { VMW_(N); __builtin_amdgcn_sched_barrier(0); } while (0)
#define LGKM0() do { asm volatile("s_waitcnt lgkmcnt(0)" ::: "memory"); \
                     __builtin_amdgcn_sched_barrier(0); } while (0)
#define SBAR() __builtin_amdgcn_sched_barrier(0)
// raw workgroup barrier: NO implicit vmcnt(0) drain (unlike __syncthreads)
#define RAWBAR() do { SBAR(); __builtin_amdgcn_s_barrier(); SBAR(); } while (0)

// fast transcendentals (bf16-tolerance OK; saturation-correct)
__device__ __forceinline__ float fexp2(float x) {
  float r; asm("v_exp_f32 %0, %1" : "=v"(r) : "v"(x)); return r;
}
__device__ __forceinline__ float frcp(float x) {
  float r; asm("v_rcp_f32 %0, %1" : "=v"(r) : "v"(x)); return r;
}
__device__ __forceinline__ float fsigmoid(float x) {
  return frcp(1.f + fexp2(-1.44269504f * x));
}
__device__ __forceinline__ float ftanh(float x) {
  return 1.f - 2.f * frcp(1.f + fexp2(2.88539008f * x));
}

// ---------------------------------------------------------------------------
// Gate-interleaved transposed weights: Wt[(j>>4)*64 + gate*16 + (j&15)][k]
__global__ void convert_w_kernel(const float* __restrict__ Wf, const float* __restrict__ Wi,
                                 const float* __restrict__ Wg, const float* __restrict__ Wo,
                                 bf16* __restrict__ Wt) {
  __shared__ float tile[64][17];
  const int k0 = blockIdx.x * 64;
  const int jb = blockIdx.y;
  const int j0 = jb * 16;
  const int t  = threadIdx.x;
  const float* srcs[4] = {Wf, Wi, Wg, Wo};
#pragma unroll
  for (int g = 0; g < 4; ++g) {
    const float* src = srcs[g];
    {
      const int jl = t & 15, kb = t >> 4;
#pragma unroll
      for (int r = 0; r < 4; ++r) {
        const int kl = kb + 16 * r;
        tile[kl][jl] = src[(size_t)(k0 + kl) * HID + (j0 + jl)];
      }
    }
    __syncthreads();
    {
      const int kk = t & 63, jl4 = t >> 6;
#pragma unroll
      for (int r = 0; r < 4; ++r) {
        const int jl = jl4 + 4 * r;
        Wt[(size_t)(jb * 64 + g * 16 + jl) * KTOT + (k0 + kk)] = (bf16)tile[kk][jl];
      }
    }
    __syncthreads();
  }
}

// fp32 -> bf16 convert of X (big-ws path)
__global__ void convert_x_kernel(const float* __restrict__ X, bf16* __restrict__ xb) {
  const int t = blockIdx.y;
  const int i = blockIdx.x * blockDim.x + threadIdx.x;
  const float4 v = ((const float4*)(X + (size_t)t * BATCH * DIN))[i];
  bf16x4 o;
  o[0] = (bf16)v.x; o[1] = (bf16)v.y; o[2] = (bf16)v.z; o[3] = (bf16)v.w;
  ((bf16x4*)(xb + (size_t)t * BATCH * DIN))[i] = o;
}

// ---------------------------------------------------------------------------
// Persistent LSTM v13: two independent batch halves (rows 0-127 / 128-255)
// interleaved in every block so each half's handoff RTT hides under the other
// half's compute. Block: 32 rows x 64 Wt-rows PER HALF; 8 waves, K-eighth
// split (6 slices of 32k), shared breg (96 VGPR); acc 2x4 frags per half.
// hseq tiles 1KB (32 rows x 16 j); store = one full 128B line per wave.
// Flags per (t, half, block); per-wave 8-producer poll (v10-proven).
__global__ __launch_bounds__(512, 2)
void lstm_v13(const bf16* __restrict__ Bt,
              const bf16* __restrict__ xb,
              bf16* __restrict__ hseq,
              const bf16* __restrict__ zb16,     // >= 1KB zeros
              float* __restrict__ outF,
              const float* __restrict__ bf_, const float* __restrict__ bi_,
              const float* __restrict__ bg_, const float* __restrict__ bo_,
              unsigned* __restrict__ flags) {    // [T][2][256], zeroed
  __shared__ f32x4 redu[8][8][64];   // 64 KiB, reused A/B with barriers

  const int tid = threadIdx.x, lane = tid & 63, wid = tid >> 6;
  const int bid = blockIdx.x;
  const int e8  = bid & 7;
  const int mh   = e8 >> 1;                      // row-group (32 rows/half)
  const int nblk = ((bid >> 3) << 1) | (e8 & 1); // bijective 0..63
  const int bn0 = nblk * 64;
  const int fr = lane & 15, fq = lane >> 4;
  const int rowA = mh * 32, rowB = 128 + mh * 32;

  // once-per-launch agent acquire: invalidate stale L2 lines (graph replays)
  if (tid == 0)
    (void)__hip_atomic_load(flags, __ATOMIC_ACQUIRE, __HIP_MEMORY_SCOPE_AGENT);
  __syncthreads();

  const int j = nblk * 16 + fr;
  const float bfv = bf_[j], biv = bi_[j], bgv = bg_[j], bov = bo_[j];
  float crA = 0.f, crB = 0.f;      // 1 cell per thread per half

  // ---- B panel -> registers, once (96 VGPR/lane), shared by both halves
  bf16x8 breg[6][4];
#pragma unroll
  for (int s = 0; s < 6; ++s) {
    const int ks = wid + 8 * s;
#pragma unroll
    for (int nf = 0; nf < 4; ++nf)
      breg[s][nf] = *(const bf16x8*)(Bt + (size_t)(bn0 + nf * 16 + fr) * KTOT
                                     + ks * 32 + fq * 8);
  }

  // A-operand slots (2 frags each): x per half + shared h ladder
  bf16x8 xA0[2], xA1[2], xB0[2], xB1[2], h2[2], h3[2], h4[2], h5[2];

  auto ldx = [&](int t2, int rowbase, int s, bf16x8 (&sl)[2]) {
    const bf16* src = xb + (size_t)t2 * BATCH * DIN + (wid + 8 * s) * 32 + fq * 8;
#pragma unroll
    for (int mf = 0; mf < 2; ++mf)
      sl[mf] = *(const bf16x8*)(src + (size_t)(rowbase + mf * 16 + fr) * DIN);
  };
  auto ldh = [&](int t2, int half, int s, bf16x8 (&sl)[2]) {
    const int c0 = (wid + 8 * s) * 32 - 512;
    const int pp = (c0 >> 4) + (fq >> 1);
    const bf16* base = (t2 == 0)
        ? zb16
        : hseq + ((((size_t)(t2 - 1) * 2 + half) << 8) + mh * 64 + pp) * 512;
    const int coloff = (fq & 1) * 8;
#pragma unroll
    for (int mf = 0; mf < 2; ++mf)
      sl[mf] = *(const bf16x8*)(base + (mf * 16 + fr) * 16 + coloff);
  };

  // per-wave poll of this wave's 8 h-producers (same (half, mh) group)
  const int pn8 = 2 * wid + ((lane & 7) >> 1) * 16 + (lane & 1);
  auto pollh = [&](int tprev, int half) {
    const unsigned* f = flags + (((size_t)tprev * 2 + half) << 8) + mh * 64 + pn8;
    const unsigned long long tt0 = __builtin_amdgcn_s_memrealtime();
    for (;;) {
      unsigned v = __hip_atomic_load(f, __ATOMIC_RELAXED,
                                     __HIP_MEMORY_SCOPE_AGENT);
      if (__all(v != 0)) break;
      __builtin_amdgcn_s_sleep(1);
      if (__builtin_amdgcn_s_memrealtime() - tt0 > (1ULL << 22)) break;  // fail-soft
    }
    asm volatile("" ::: "memory");
    __builtin_amdgcn_sched_barrier(0);
  };

  auto dump = [&](f32x4 (&acc)[2][4]) {
#pragma unroll
    for (int mf = 0; mf < 2; ++mf)
#pragma unroll
      for (int nf = 0; nf < 4; ++nf)
        redu[wid][mf * 4 + nf][lane] = acc[mf][nf];
  };

  // owner cell: row = wid*4+fq (of 32), col j. frag mf=wid>>2,
  // lane_sel=(wid&3)*16+fr, reg=fq  (C/D: col=lane&15, row=(lane>>4)*4+reg)
  auto finish = [&](int t2, int half, float& cre) {
    const int mf_c = wid >> 2;
    const int lsel = (wid & 3) * 16 + fr;
    float z[4];
#pragma unroll
    for (int nf = 0; nf < 4; ++nf) {
      float s_ = 0.f;
#pragma unroll
      for (int s = 0; s < 8; ++s)
        s_ += ((const float*)&redu[s][mf_c * 4 + nf][lsel])[fq];
      z[nf] = s_;
    }
    const float fg = fsigmoid(z[0] + bfv);
    const float ig = fsigmoid(z[1] + biv);
    const float gg = ftanh(z[2] + bgv);
    const float og = fsigmoid(z[3] + bov);
    cre = fg * cre + ig * gg;
    const float h = og * ftanh(cre);
    // hseq tile store: one full 128B line per wave
    bf16* tile = hseq + ((((size_t)t2 * 2 + half) << 8) + mh * 64 + nblk) * 512;
    store_bf16_sc(&tile[wid * 64 + lane], (bf16)h);
    const int rowg = half * 128 + mh * 32 + wid * 4 + fq;
    outF[(size_t)t2 * BHSZ + (size_t)rowg * HID + j] = h;
    if (t2 == T_STEPS - 1)
      outF[(size_t)(T_STEPS + 1) * BHSZ + (size_t)rowg * HID + j] = cre;
  };

  auto setflag = [&](int t2, int half) {
    __hip_atomic_store(&flags[(((size_t)t2 * 2 + half) << 8) + mh * 64 + nblk],
                       1u, __ATOMIC_RELAXED, __HIP_MEMORY_SCOPE_AGENT);
  };

#define MFMA8(ACC, SL, S) do {                                              \
    __builtin_amdgcn_s_setprio(1);                                          \
    _Pragma("unroll")                                                       \
    for (int mf_ = 0; mf_ < 2; ++mf_) {                                     \
      _Pragma("unroll")                                                     \
      for (int nf_ = 0; nf_ < 4; ++nf_)                                     \
        ACC[mf_][nf_] = __builtin_amdgcn_mfma_f32_16x16x32_bf16(            \
            SL[mf_], breg[S][nf_], ACC[mf_][nf_], 0, 0, 0);                 \
    }                                                                       \
    __builtin_amdgcn_s_setprio(0);                                          \
  } while (0)

  // prologue: x of step 0 for both halves; xA drained, xB in flight
  ldx(0, rowA, 0, xA0); SBAR(); ldx(0, rowA, 1, xA1); SBAR();
  ldx(0, rowB, 0, xB0); SBAR(); ldx(0, rowB, 1, xB1); SBAR();
  VMW(4);

#pragma unroll 1
  for (int t = 0; t < T_STEPS; ++t) {
    f32x4 accA[2][4] = {}, accB[2][4] = {};
    // ---- half A: x MFMAs, poll, issue h loads
    MFMA8(accA, xA0, 0); MFMA8(accA, xA1, 1);
    if (t > 0) pollh(t - 1, 0);
    ldh(t, 0, 2, h2); SBAR(); ldh(t, 0, 3, h3); SBAR();
    ldh(t, 0, 4, h4); SBAR(); ldh(t, 0, 5, h5); SBAR();
    // half B x MFMAs hide A's h RTT (also completes [outB, xB'] leftovers)
    VMW(8);
    MFMA8(accB, xB0, 0); MFMA8(accB, xB1, 1);
    // half A h MFMAs, counted ladder
    VMW(6); MFMA8(accA, h2, 2);
    VMW(4); MFMA8(accA, h3, 3);
    VMW(2); MFMA8(accA, h4, 4);
    VMW(0); MFMA8(accA, h5, 5);
    dump(accA); LGKM0(); RAWBAR();
    // ---- half B: poll + issue h loads; A's reduce/epilogue hides B's RTT
    if (t > 0) pollh(t - 1, 1);
    ldh(t, 1, 2, h2); SBAR(); ldh(t, 1, 3, h3); SBAR();
    ldh(t, 1, 4, h4); SBAR(); ldh(t, 1, 5, h5); SBAR();
    finish(t, 0, crA);                       // + hseqA, outA stores
    if (t + 1 < T_STEPS) {
      ldx(t + 1, rowA, 0, xA0); SBAR(); ldx(t + 1, rowA, 1, xA1); SBAR();
      // Q=[hB8, stA, outA, xA4]: ack stA (and hB) -> leave [outA, xA4]
      VMW(5);
    } else {
      VMW(0);
    }
    RAWBAR();
    if (tid == 0) setflag(t, 0);
    // ---- half B h MFMAs (all landed), dump, finish
    MFMA8(accB, h2, 2); MFMA8(accB, h3, 3);
    MFMA8(accB, h4, 4); MFMA8(accB, h5, 5);
    dump(accB); LGKM0(); RAWBAR();
    finish(t, 1, crB);                       // + hseqB, outB stores
    if (t + 1 < T_STEPS) {
      ldx(t + 1, rowB, 0, xB0); SBAR(); ldx(t + 1, rowB, 1, xB1); SBAR();
      // Q=[outA, xA4, stB, outB, xB4]: ack stB -> leave [outB, xB4]
      VMW(4);
    } else {
      VMW(0);
    }
    RAWBAR();
    if (tid == 0) setflag(t, 1);
  }
#undef MFMA8
}

// ---------------------------------------------------------------------------
// Fallback (small ws): round-5 MODE-1 path verbatim (fp32 A from X / out).
__global__ __launch_bounds__(512, 2)
void lstm_fb(const bf16* __restrict__ Bt,
             const float* __restrict__ X,
             const float* __restrict__ zbF,
             float* __restrict__ outF,
             const float* __restrict__ bf_, const float* __restrict__ bi_,
             const float* __restrict__ bg_, const float* __restrict__ bo_,
             unsigned* __restrict__ flags) {
  __shared__ f32x4 redu[8][16][64];
  const int tid = threadIdx.x, lane = tid & 63, wid = tid >> 6;
  const int bid = blockIdx.x;
  const int xcd = bid & 7, sl = bid >> 3;
  const int nblk = xcd * 8 + (sl & 7);
  const int mblk = sl >> 3;
  const int bm0 = mblk * 64;
  const int bn0 = nblk * 64;
  const int fr = lane & 15, fq = lane >> 4;

  if (tid == 0)
    (void)__hip_atomic_load(flags, __ATOMIC_ACQUIRE, __HIP_MEMORY_SCOPE_AGENT);
  __syncthreads();

  const int j = nblk * 16 + fr;
  const float bfv = bf_[j], biv = bi_[j], bgv = bg_[j], bov = bo_[j];
  float cr[2] = {0.f, 0.f};

  bf16x8 breg[6][4];
#pragma unroll
  for (int s = 0; s < 6; ++s) {
    const int ks = wid + 8 * s;
#pragma unroll
    for (int nf = 0; nf < 4; ++nf)
      breg[s][nf] = *(const bf16x8*)(Bt + (size_t)(bn0 + nf * 16 + fr) * KTOT
                                     + ks * 32 + fq * 8);
  }

  bf16x8 afp[2][4];

  auto poll = [&](int tprev) {
    const unsigned* f = flags + (size_t)tprev * 256 + mblk * 64;
    const unsigned long long tt0 = __builtin_amdgcn_s_memrealtime();
    for (;;) {
      unsigned v = __hip_atomic_load(f + lane, __ATOMIC_RELAXED,
                                     __HIP_MEMORY_SCOPE_AGENT);
      if (__all(v != 0)) break;
      __builtin_amdgcn_s_sleep(2);
      if (__builtin_amdgcn_s_memrealtime() - tt0 > (1ULL << 22)) break;
    }
    asm volatile("" ::: "memory");
    __builtin_amdgcn_sched_barrier(0);
  };

  auto loadA = [&](int t2, int s, int p) __attribute__((always_inline)) {
    const int ks = wid + 8 * s;
    const int k = ks * 32 + fq * 8;
    if (s == 2 && t2 > 0) poll(t2 - 1);
    const float* src; int ld, kk;
    if (s < 2) { src = X + (size_t)t2 * BATCH * DIN; ld = DIN; kk = k; }
    else {
      src = (t2 == 0) ? zbF : outF + (size_t)(t2 - 1) * BHSZ;
      ld = HID; kk = k - 512;
    }
#pragma unroll
    for (int mf = 0; mf < 4; ++mf) {
      const float* q = src + (size_t)(bm0 + mf * 16 + fr) * ld + kk;
      const f32x4 lo = *(const f32x4*)q;
      const f32x4 hi = *(const f32x4*)(q + 4);
      bf16x8 v;
      v[0] = (bf16)lo[0]; v[1] = (bf16)lo[1]; v[2] = (bf16)lo[2]; v[3] = (bf16)lo[3];
      v[4] = (bf16)hi[0]; v[5] = (bf16)hi[1]; v[6] = (bf16)hi[2]; v[7] = (bf16)hi[3];
      afp[p][mf] = v;
    }
  };

  loadA(0, 0, 0);

#pragma unroll 1
  for (int t = 0; t < T_STEPS; ++t) {
    f32x4 acc[4][4] = {};
#pragma unroll
    for (int s = 0; s < 6; ++s) {
      if (s < 5)                loadA(t, s + 1, (s + 1) & 1);
      else if (t + 1 < T_STEPS) loadA(t + 1, 0, 0);
      __builtin_amdgcn_s_setprio(1);
#pragma unroll
      for (int mf = 0; mf < 4; ++mf)
#pragma unroll
        for (int nf = 0; nf < 4; ++nf)
          acc[mf][nf] = __builtin_amdgcn_mfma_f32_16x16x32_bf16(
              afp[s & 1][mf], breg[s][nf], acc[mf][nf], 0, 0, 0);
      __builtin_amdgcn_s_setprio(0);
    }

#pragma unroll
    for (int mf = 0; mf < 4; ++mf)
#pragma unroll
      for (int nf = 0; nf < 4; ++nf)
        redu[wid][mf * 4 + nf][lane] = acc[mf][nf];
    __syncthreads();

    const int fbase = (wid >> 1) * 4;
    const int rh = wid & 1;
    float z[2][4];
#pragma unroll
    for (int e = 0; e < 2; ++e) {
      const int rloc = rh * 8 + fq * 2 + e;
      const int lsel = (rloc >> 2) * 16 + fr;
      const int rc = rloc & 3;
#pragma unroll
      for (int nf = 0; nf < 4; ++nf) {
        float sum = 0.f;
#pragma unroll
        for (int s = 0; s < 8; ++s)
          sum += ((const float*)&redu[s][fbase + nf][lsel])[rc];
        z[e][nf] = sum;
      }
    }

    float* outSl = outF + (size_t)t * BHSZ;
#pragma unroll
    for (int e = 0; e < 2; ++e) {
      const float fg = 1.f / (1.f + expf(-(z[e][0] + bfv)));
      const float ig = 1.f / (1.f + expf(-(z[e][1] + biv)));
      const float gg = tanhf(z[e][2] + bgv);
      const float og = 1.f / (1.f + expf(-(z[e][3] + bov)));
      cr[e] = fg * cr[e] + ig * gg;
      const float h = og * tanhf(cr[e]);
      const int m = bm0 + wid * 8 + fq * 2 + e;
      const size_t off = (size_t)m * HID + j;
      __hip_atomic_store(&outSl[off], h, __ATOMIC_RELAXED,
                         __HIP_MEMORY_SCOPE_AGENT);
      if (t == T_STEPS - 1)
        outF[(size_t)(T_STEPS + 1) * BHSZ + off] = cr[e];
    }
    asm volatile("s_waitcnt vmcnt(0)" ::: "memory");
    __syncthreads();
    if (tid == 0)
      __hip_atomic_store(&flags[(size_t)t * 256 + mblk * 64 + nblk], 1u,
                         __ATOMIC_RELAXED, __HIP_MEMORY_SCOPE_AGENT);
  }
}

// ---------------------------------------------------------------------------
extern "C" void kernel_launch(void* const* d_in, const int* in_sizes, int n_in,
                              void* d_out, int out_size, void* d_ws, size_t ws_size,
                              hipStream_t stream) {
  const float* X   = (const float*)d_in[0];
  const float* Wf  = (const float*)d_in[1];
  const float* bf_ = (const float*)d_in[2];
  const float* Wi  = (const float*)d_in[3];
  const float* bi_ = (const float*)d_in[4];
  const float* Wg  = (const float*)d_in[5];
  const float* bg_ = (const float*)d_in[6];
  const float* Wo  = (const float*)d_in[7];
  const float* bo_ = (const float*)d_in[8];
  float* out = (float*)d_out;

  const size_t WtB   = (size_t)NOUT * KTOT * 2;            // 12.58 MB
  const size_t zBb   = BHSZ * 4;                           // 1 MB zeros
  const size_t flagB = (size_t)T_STEPS * 2 * 256 * 4;      // 512 KB
  const size_t XbB   = (size_t)T_STEPS * BATCH * DIN * 2;  // 67.1 MB
  const size_t HsB   = (size_t)T_STEPS * 2 * 256 * 1024;   // 134.2 MB (tiled)

  char* ws = (char*)d_ws;
  bf16*     Wt    = (bf16*)ws;              ws += WtB;
  float*    zbF   = (float*)(void*)ws;      ws += zBb;
  unsigned* flags = (unsigned*)(void*)ws;   ws += flagB;

  const bool big = ws_size >= WtB + zBb + flagB + XbB + HsB + (1u << 20);
  bf16* xbp = nullptr;  bf16* hseq = nullptr;
  if (big) {
    xbp  = (bf16*)ws;   ws += XbB;
    hseq = (bf16*)ws;
  }

  // zeros + flags (re-zeroed every launch -> deterministic)
  hipMemsetAsync(zbF, 0, zBb + flagB, stream);

  convert_w_kernel<<<dim3(KTOT / 64, NOUT / 64), 256, 0, stream>>>(Wf, Wi, Wg, Wo, Wt);

  if (big) {
    convert_x_kernel<<<dim3(BATCH * DIN / 4 / 256, T_STEPS), 256, 0, stream>>>(X, xbp);
    lstm_v13<<<256, 512, 0, stream>>>(Wt, xbp, hseq, (const bf16*)zbF, out,
                                      bf_, bi_, bg_, bo_, flags);
  } else {
    lstm_fb<<<256, 512, 0, stream>>>(Wt, X, zbF, out,
                                     bf_, bi_, bg_, bo_, flags);
  }

  // hx = outputs[T-1] (cx stored by the kernel)
  hipMemcpyAsync(out + (size_t)T_STEPS * BHSZ, out + (size_t)(T_STEPS - 1) * BHSZ,
                 BHSZ * 4, hipMemcpyDeviceToDevice, stream);
}